// Round 6
// baseline (239.518 us; speedup 1.0000x reference)
//
#include <hip/hip_runtime.h>

// DWT db4 depthwise stride-2 decomposition.
// x: [B=32, T=16384, C=64] f32 -> out: [B, T2=8190, 2C=128] f32
// out[b,t,c]    = sum_k lo[k] * x[b, reflect(2t+k-1), c]      (c < 64)
// out[b,t,64+c] = sum_k hi[k] * x[b, reflect(2t+k-1), c]
// reflect: m<0 -> -m ; m>T-1 -> 2(T-1)-m
//
// R6: wave-private barrier-free software pipeline. R1-R5 all pinned at
// ~2.6 TB/s regardless of structure; model says per-CU read miss-queue +
// phase convoys (reads idle while compute/store phases run; __syncthreads
// drains vmcnt(0) so barrier kernels can't keep prefetch in flight).
// Here: block = 1 wave, private 10 KB LDS tile, loop over 8 tiles:
//   issue 10 global dwordx4 loads (tile s+1) -> REGISTERS (precise
//   per-register waitcnt, compiler can't over-wait), sched_barrier(0) pins
//   them before compute, compute tile s from LDS + nt-store, then ds_write
//   regs -> LDS (vmcnt wait lands here, after compute). Loads are in flight
//   during 100% of compute, every wave, no barriers anywhere.

#define BT    32
#define TT    16384
#define CC    64        // floats per input row
#define T2    8190      // T/2 - 2
#define OC    128       // 2*CC
#define WSTEP 16        // outputs per wave-step
#define SROWS 40        // staged rows per step (needs 38 = 2*WSTEP+6)
#define NLD   10        // 10 x (64 lanes x 16 B) = 40 rows
#define STRIP 8         // steps per wave
#define NSTEP 512       // ceil(T2 / WSTEP) steps per batch
#define NW    (NSTEP / STRIP)   // 64 strips per batch

typedef float vf4 __attribute__((ext_vector_type(4)));

__device__ __forceinline__ int reflect_row(int m) {
    int mm = m < 0 ? -m : m;
    return mm > (TT - 1) ? 2 * (TT - 1) - mm : mm;
}

__global__ __launch_bounds__(64) void dwt_db4_pipe_kernel(
    const float* __restrict__ x,
    const float* __restrict__ dec_lo,
    const float* __restrict__ dec_hi,
    float* __restrict__ out)
{
    __shared__ float lds[SROWS * CC];   // 40 rows * 256 B = 10240 B, wave-private

    const int lane = threadIdx.x;       // 0..63
    const int w    = blockIdx.x;        // strip 0..63
    const int b    = blockIdx.y;        // batch 0..31
    const int s0   = w * STRIP;

    const int cg = lane & 15;           // channel group (4 ch via vf4)
    const int ls = lane >> 4;           // t-slot 0..3 (4 outputs each)
    const int c4 = cg * 4;

    float flo[8], fhi[8];
    #pragma unroll
    for (int k = 0; k < 8; ++k) { flo[k] = dec_lo[k]; fhi[k] = dec_hi[k]; }

    const float* __restrict__ xb = x + (size_t)b * TT * CC;

    // slot decomposition for staging: slot = it*64 + lane
    //   row r = slot >> 4  (0..39), float col = (slot & 15) * 4
    const int sl_r = lane >> 4;             // + it*4 per iteration
    const int sl_c = (lane & 15) * 4;

    vf4 stg[NLD];

    // ---- prologue: load + write tile s0 ----
    {
        const int mbase = 32 * s0 - 1;
        #pragma unroll
        for (int it = 0; it < NLD; ++it) {
            const int r  = it * 4 + sl_r;
            const int mm = reflect_row(mbase + r);
            stg[it] = *reinterpret_cast<const vf4*>(xb + (size_t)mm * CC + sl_c);
        }
        #pragma unroll
        for (int it = 0; it < NLD; ++it) {
            const int slot = it * 64 + lane;
            *reinterpret_cast<vf4*>(&lds[slot * 4]) = stg[it];
        }
    }

    #pragma unroll
    for (int i = 0; i < STRIP; ++i) {
        const int s = s0 + i;

        // ---- issue prefetch of tile s+1 into registers (no wait) ----
        if (i + 1 < STRIP) {
            const int mbase = 32 * (s + 1) - 1;
            #pragma unroll
            for (int it = 0; it < NLD; ++it) {
                const int r  = it * 4 + sl_r;
                const int mm = reflect_row(mbase + r);
                stg[it] = *reinterpret_cast<const vf4*>(xb + (size_t)mm * CC + sl_c);
            }
        }
        // pin: loads issued before compute, not sunk into it
        __builtin_amdgcn_sched_barrier(0);

        // ---- compute tile s from LDS ----
        // thread outputs: t = 16s + 4*ls + j, j=0..3; local rows 8ls+2j+k
        vf4 wnd[14];
        #pragma unroll
        for (int k = 0; k < 14; ++k)
            wnd[k] = *reinterpret_cast<const vf4*>(&lds[(8 * ls + k) * CC + c4]);

        vf4 alo[4], ahi[4];
        #pragma unroll
        for (int j = 0; j < 4; ++j) { alo[j] = (vf4)0.0f; ahi[j] = (vf4)0.0f; }

        #pragma unroll
        for (int j = 0; j < 4; ++j) {
            #pragma unroll
            for (int k = 0; k < 8; ++k) {
                const vf4 v = wnd[2 * j + k];
                alo[j] += flo[k] * v;
                ahi[j] += fhi[k] * v;
            }
        }

        const int tbase = WSTEP * s + 4 * ls;
        float* __restrict__ ob = out + (size_t)b * T2 * OC + (size_t)tbase * OC;
        #pragma unroll
        for (int j = 0; j < 4; ++j) {
            if (tbase + j < T2) {
                __builtin_nontemporal_store(alo[j],
                    reinterpret_cast<vf4*>(ob + (size_t)j * OC + c4));
                __builtin_nontemporal_store(ahi[j],
                    reinterpret_cast<vf4*>(ob + (size_t)j * OC + CC + c4));
            }
        }
        __builtin_amdgcn_sched_barrier(0);

        // ---- ds_write arrived prefetch into (now-free) LDS tile ----
        // (the vmcnt wait for stg lands here, after compute)
        if (i + 1 < STRIP) {
            #pragma unroll
            for (int it = 0; it < NLD; ++it) {
                const int slot = it * 64 + lane;
                *reinterpret_cast<vf4*>(&lds[slot * 4]) = stg[it];
            }
        }
    }
}

extern "C" void kernel_launch(void* const* d_in, const int* in_sizes, int n_in,
                              void* d_out, int out_size, void* d_ws, size_t ws_size,
                              hipStream_t stream)
{
    const float* x      = (const float*)d_in[0];
    const float* dec_lo = (const float*)d_in[1];
    const float* dec_hi = (const float*)d_in[2];
    float*       out    = (float*)d_out;

    dim3 block(64);
    dim3 grid(NW, BT);   // 64 strips x 32 batches = 2048 waves, 8 blocks/CU

    hipLaunchKernelGGL(dwt_db4_pipe_kernel, grid, block, 0, stream,
                       x, dec_lo, dec_hi, out);
}